// Round 2
// baseline (340.048 us; speedup 1.0000x reference)
//
#include <hip/hip_runtime.h>
#include <stdint.h>

#define NN 512
#define PAIR 128
#define SINGLE 256

#define GAINv 1.5927812698663017f
#define RS2 0.70710678118654752f

typedef unsigned int uint;
typedef unsigned short ushort;
typedef short bf16x8 __attribute__((ext_vector_type(8)));
typedef float f32x4 __attribute__((ext_vector_type(4)));

__device__ __forceinline__ ushort f2b(float f){
  union{float f;uint i;}v; v.f=f;
  uint x=v.i;
  return (ushort)((x + 0x7FFFu + ((x>>16)&1u))>>16);  // RNE, finite inputs only
}
__device__ __forceinline__ float tanh_fast(float x){
  float xc = fminf(fmaxf(x,-8.f),8.f);
  float e = __expf(2.f*xc);
  return (e-1.f)*__builtin_amdgcn_rcpf(e+1.f);
}

// ---------------- k1: g1 spin-partials of h_one (plain stores) + W2^T -> bf16 -----
__global__ __launch_bounds__(256) void k1_prep(const float* __restrict__ h_one,
                                               const float* __restrict__ w2,
                                               float* __restrict__ g1part,
                                               ushort* __restrict__ wt)
{
  const int b = blockIdx.x, t = threadIdx.x;
  if(b < 8){
    const int rb = b*64;
    float s = 0.f;
    for(int i=0;i<64;i++) s += h_one[(size_t)(rb+i)*SINGLE + t];
    g1part[b*SINGLE + t] = s;                    // blocks 0..3 spin0, 4..7 spin1
  } else {
    const int bb = b-8;                          // 16 rows of W2 each
    for(int e=t; e<16*128; e+=256){
      int kl = e>>7, n = e&127;
      int k = bb*16 + kl;
      wt[n*128 + k] = f2b(w2[(size_t)k*128 + n]);  // wt[n][k] = bf16(W2[k][n])
    }
  }
}

// ---------------- k2: gterm partials (plain stores, no atomics) -------------------
__global__ __launch_bounds__(256) void k2_gterm(const float* __restrict__ g1part,
                                                const float* __restrict__ wg,
                                                float* __restrict__ gtermpart)
{
  __shared__ float g1m[512];
  const int t = threadIdx.x;
  g1m[t]     = (g1part[t]      + g1part[256+t]  + g1part[512+t]  + g1part[768+t])  * (1.f/256.f);
  g1m[t+256] = (g1part[1024+t] + g1part[1280+t] + g1part[1536+t] + g1part[1792+t]) * (1.f/256.f);
  __syncthreads();
  const int fb = blockIdx.x*64;
  float s = 0.f;
  for(int f=fb; f<fb+64; f++)
    s += g1m[f]*wg[(size_t)f*SINGLE + t];
  gtermpart[blockIdx.x*SINGLE + t] = s;
}

// ---------------- k3: h_two fused GEMM, LDS-free / barrier-free / atomic-free -----
// block = (sender spin, receiver j). 4 waves; wave w owns output cols n in
// [w*32, w*32+32). 16 chunks of 16 sender rows; A staged to registers, W2^T
// fragments register-resident, g2 accumulated in registers (quarter w per wave,
// via rotated stage order so all indexing is compile-time static).
__global__ __launch_bounds__(256, 3) void k3_htwo(
    const float* __restrict__ h_two,
    const float* __restrict__ b2,
    const ushort* __restrict__ wt,
    float* __restrict__ g2acc,
    float* __restrict__ out_h2)
{
  const int tid  = threadIdx.x;
  const int w    = tid>>6, lane = tid&63;
  const int lq   = lane>>4, lr = lane&15;
  const int spin = blockIdx.x >> 9;
  const int j    = blockIdx.x & 511;

  // A-op fragments (Wt rows = output features n). Stage slot s covers k-quarter
  // q(s) = (s+w)&3 so that slot 0 is always this wave's g2 quarter.
  bf16x8 af[2][4];
  #pragma unroll
  for(int nt=0;nt<2;nt++){
    const int n = w*32 + nt*16 + lr;
    #pragma unroll
    for(int s=0;s<4;s++){
      const int q = (s + w) & 3;
      af[nt][s] = *(const bf16x8*)(wt + n*128 + q*32 + lq*8);
    }
  }
  // bias for this lane's output columns (used as MFMA C-in)
  f32x4 bias[2];
  #pragma unroll
  for(int nt=0;nt<2;nt++){
    const float4 bv = *(const float4*)(b2 + w*32 + nt*16 + lq*4);
    bias[nt] = (f32x4){bv.x, bv.y, bv.z, bv.w};
  }

  const size_t row0 = (size_t)spin*256 + lr;
  const float* rp = h_two + (row0*NN + j)*PAIR;
  float*       op = out_h2 + (row0*NN + j)*PAIR;
  const size_t cstep = (size_t)16*NN*PAIR;     // 16 sender rows

  float g2r[8] = {0.f,0.f,0.f,0.f,0.f,0.f,0.f,0.f};

  #pragma unroll 1
  for(int c=0;c<16;c++){
    const float* rb = rp + (size_t)c*cstep;
    // stage 16 rows x full K into registers (f32)
    float4 S[8];
    #pragma unroll
    for(int s=0;s<4;s++){
      const int q = (s + w) & 3;
      S[s*2]   = *(const float4*)(rb + q*32 + lq*8);
      S[s*2+1] = *(const float4*)(rb + q*32 + lq*8 + 4);
    }
    // residual re-read (same 128B this wave just staged in slot 0 -> L1/L2 hot)
    const float4 R0 = *(const float4*)(rb + w*32 + lq*4);
    const float4 R1 = *(const float4*)(rb + w*32 + 16 + lq*4);

    // g2 partial for quarter w (slot 0), f32 precision
    g2r[0]+=S[0].x; g2r[1]+=S[0].y; g2r[2]+=S[0].z; g2r[3]+=S[0].w;
    g2r[4]+=S[1].x; g2r[5]+=S[1].y; g2r[6]+=S[1].z; g2r[7]+=S[1].w;

    // convert + MFMA: D[n][m] = sum_k W2[k][n]*h2[m][k] + b2[n]
    f32x4 acc0 = bias[0], acc1 = bias[1];
    #pragma unroll
    for(int s=0;s<4;s++){
      bf16x8 bfr;
      const float* sv = (const float*)&S[s*2];
      #pragma unroll
      for(int e=0;e<8;e++) bfr[e] = (short)f2b(sv[e]);
      acc0 = __builtin_amdgcn_mfma_f32_16x16x32_bf16(af[0][s], bfr, acc0, 0,0,0);
      acc1 = __builtin_amdgcn_mfma_f32_16x16x32_bf16(af[1][s], bfr, acc1, 0,0,0);
    }

    // epilogue: tanh*gain + residual, nontemporal f32 store
    float* ob = op + (size_t)c*cstep + w*32 + lq*4;
    f32x4 o0, o1;
    o0[0] = (R0.x + GAINv*tanh_fast(acc0[0]))*RS2;
    o0[1] = (R0.y + GAINv*tanh_fast(acc0[1]))*RS2;
    o0[2] = (R0.z + GAINv*tanh_fast(acc0[2]))*RS2;
    o0[3] = (R0.w + GAINv*tanh_fast(acc0[3]))*RS2;
    o1[0] = (R1.x + GAINv*tanh_fast(acc1[0]))*RS2;
    o1[1] = (R1.y + GAINv*tanh_fast(acc1[1]))*RS2;
    o1[2] = (R1.z + GAINv*tanh_fast(acc1[2]))*RS2;
    o1[3] = (R1.w + GAINv*tanh_fast(acc1[3]))*RS2;
    __builtin_nontemporal_store(o0, (f32x4*)ob);
    __builtin_nontemporal_store(o1, (f32x4*)(ob+16));
  }

  // reduce g2 partials over the 16 lr lanes, then plain stores (no atomics)
  #pragma unroll
  for(int m=1;m<16;m<<=1){
    #pragma unroll
    for(int q=0;q<8;q++) g2r[q] += __shfl_xor(g2r[q], m, 64);
  }
  if(lr < 2){
    f32x4 v;
    if(lr==0){ v[0]=g2r[0]; v[1]=g2r[1]; v[2]=g2r[2]; v[3]=g2r[3]; }
    else     { v[0]=g2r[4]; v[1]=g2r[5]; v[2]=g2r[6]; v[3]=g2r[7]; }
    *(f32x4*)(g2acc + ((size_t)spin*NN + j)*PAIR + w*32 + lq*8 + lr*4) = v;
  }
}

// ---------------- k4: h_one path — 2 rows/block (256 blocks = 1/CU) ---------------
__global__ __launch_bounds__(256) void k4_hone(
    const float* __restrict__ h_one,
    const float* __restrict__ w1,
    const float* __restrict__ b1,
    const float* __restrict__ g2acc,
    const float* __restrict__ gtermpart,
    float* __restrict__ out_h1)
{
  __shared__ float onein[2][512];
  const int n  = threadIdx.x;
  const int r0 = blockIdx.x*2;
  #pragma unroll
  for(int rr=0; rr<2; rr++){
    onein[rr][n] = h_one[(size_t)(r0+rr)*SINGLE + n];
    int sp = n>>7, p = n&127;
    onein[rr][256+n] = g2acc[((size_t)sp*NN + (r0+rr))*PAIR + p] * (1.f/256.f);
  }
  float gt = 0.f;
  #pragma unroll
  for(int bb=0;bb<8;bb++) gt += gtermpart[bb*256+n];
  __syncthreads();
  float a0=0.f, a1=0.f;
  for(int f=0; f<512; f++){
    float wv = w1[(size_t)f*SINGLE + n];
    a0 += onein[0][f]*wv;
    a1 += onein[1][f]*wv;
  }
  const float bn = b1[n];
  float x0 = (a0 + bn + gt)*RS2;
  float x1 = (a1 + bn + gt)*RS2;
  out_h1[(size_t)r0*SINGLE + n]     = (onein[0][n] + GAINv*tanh_fast(x0))*RS2;
  out_h1[(size_t)(r0+1)*SINGLE + n] = (onein[1][n] + GAINv*tanh_fast(x1))*RS2;
}

extern "C" void kernel_launch(void* const* d_in, const int* in_sizes, int n_in,
                              void* d_out, int out_size, void* d_ws, size_t ws_size,
                              hipStream_t stream)
{
  const float* h_one = (const float*)d_in[0];
  const float* h_two = (const float*)d_in[1];
  const float* W1    = (const float*)d_in[2];
  const float* b1    = (const float*)d_in[3];
  const float* Wg    = (const float*)d_in[4];
  const float* W2    = (const float*)d_in[5];
  const float* b2    = (const float*)d_in[6];

  float* wsf       = (float*)d_ws;
  float* g2acc     = wsf;                        // [2][512][128] f32 sums (plain stores)
  ushort* wt       = (ushort*)(wsf + 131072);    // W2^T bf16 [n][k], 16384 elems
  float* g1part    = wsf + 139264;               // [8][256] spin partial sums
  float* gtermpart = wsf + 141312;               // [8][256] gterm partials

  float* out_h1 = (float*)d_out;
  float* out_h2 = out_h1 + 131072;

  k1_prep <<<16,   256, 0, stream>>>(h_one, W2, g1part, wt);
  k2_gterm<<<8,    256, 0, stream>>>(g1part, Wg, gtermpart);
  k3_htwo <<<1024, 256, 0, stream>>>(h_two, b2, wt, g2acc, out_h2);
  k4_hone <<<256,  256, 0, stream>>>(h_one, W1, b1, g2acc, gtermpart, out_h1);
}

// Round 3
// 314.661 us; speedup vs baseline: 1.0807x; 1.0807x over previous
//
#include <hip/hip_runtime.h>
#include <stdint.h>

#define NN 512
#define PAIR 128
#define SINGLE 256

#define GAINv 1.5927812698663017f
#define RS2 0.70710678118654752f

typedef unsigned int uint;
typedef unsigned short ushort;
typedef short bf16x8 __attribute__((ext_vector_type(8)));
typedef float f32x4 __attribute__((ext_vector_type(4)));

__device__ __forceinline__ ushort f2b(float f){
  union{float f;uint i;}v; v.f=f;
  uint x=v.i;
  return (ushort)((x + 0x7FFFu + ((x>>16)&1u))>>16);  // RNE, finite inputs only
}
__device__ __forceinline__ float b2f_lo(uint u){ union{uint i;float f;}v; v.i=u<<16; return v.f; }
__device__ __forceinline__ float b2f_hi(uint u){ union{uint i;float f;}v; v.i=u&0xFFFF0000u; return v.f; }
__device__ __forceinline__ float tanh_fast(float x){
  float xc = fminf(fmaxf(x,-8.f),8.f);
  float e = __expf(2.f*xc);
  return (e-1.f)*__builtin_amdgcn_rcpf(e+1.f);
}

// ---------------- k1: g1 spin-partials + W2^T->bf16 + zero g2acc ------------------
__global__ __launch_bounds__(256) void k1_prep(const float* __restrict__ h_one,
                                               const float* __restrict__ w2,
                                               float* __restrict__ g1part,
                                               ushort* __restrict__ wt,
                                               float* __restrict__ g2acc)
{
  const int b = blockIdx.x, t = threadIdx.x;
  if(b < 8){
    const int rb = b*64;
    float s = 0.f;
    for(int i=0;i<64;i++) s += h_one[(size_t)(rb+i)*SINGLE + t];
    g1part[b*SINGLE + t] = s;                    // blocks 0..3 spin0, 4..7 spin1
  } else if(b < 16){
    const int bb = b-8;                          // 16 rows of W2 each
    for(int e=t; e<16*128; e+=256){
      int kl = e>>7, n = e&127;
      int k = bb*16 + kl;
      wt[n*128 + k] = f2b(w2[(size_t)k*128 + n]);  // wt[n][k] = bf16(W2[k][n]), linear
    }
  } else {
    // zero g2acc: 131072 floats = 32768 f32x4, 8 blocks
    f32x4 z = (f32x4){0.f,0.f,0.f,0.f};
    f32x4* dst = (f32x4*)g2acc + (size_t)(b-16)*4096;
    for(int q=t; q<4096; q+=256) dst[q] = z;
  }
}

// ---------------- k2: gterm partials (plain stores, no atomics) -------------------
__global__ __launch_bounds__(256) void k2_gterm(const float* __restrict__ g1part,
                                                const float* __restrict__ wg,
                                                float* __restrict__ gtermpart)
{
  __shared__ float g1m[512];
  const int t = threadIdx.x;
  g1m[t]     = (g1part[t]      + g1part[256+t]  + g1part[512+t]  + g1part[768+t])  * (1.f/256.f);
  g1m[t+256] = (g1part[1024+t] + g1part[1280+t] + g1part[1536+t] + g1part[1792+t]) * (1.f/256.f);
  __syncthreads();
  const int fb = blockIdx.x*64;
  float s = 0.f;
  for(int f=fb; f<fb+64; f++)
    s += g1m[f]*wg[(size_t)f*SINGLE + t];
  gtermpart[blockIdx.x*SINGLE + t] = s;
}

// ---------------- k3: h_two fused GEMM, 16i x 4j tile, swizzled 16KB LDS ----------
// 4 waves; wave w owns output features n in [w*32, w*32+32), all 64 tile rows.
// W2^T fragments register-resident (from L2). At staged coalesced f32->bf16 into
// XOR-swizzled LDS (elem ^= (row&7)<<3): ds_read_b128 conflicts 16-way -> 2-way.
__global__ __launch_bounds__(256, 4) void k3_htwo(
    const float* __restrict__ h_two,
    const float* __restrict__ b2,
    const ushort* __restrict__ wt,
    float* __restrict__ g2acc,
    float* __restrict__ out_h2)
{
  __shared__ __align__(16) ushort At[64*128];   // bf16, rows r=di*4+dj, swizzled
  const int tid = threadIdx.x;
  const int w = tid>>6, lane = tid&63;
  const int lq = lane>>4, lr = lane&15;
  const int bi = blockIdx.x & 31, bj = blockIdx.x >> 5;
  const int i0 = bi*16, j0 = bj*4;
  const int spin = bi>>4;

  // stage 16 i x 4 j x 128 k: coalesced f32 read -> bf16 -> swizzled LDS write
  #pragma unroll
  for(int rep=0;rep<8;rep++){
    const int e = rep*1024 + tid*4;            // flat elem: e = r*128 + k
    const int di = e>>9, c = e&511;
    const float4 v = *(const float4*)(h_two + ((size_t)(i0+di)*NN + j0)*PAIR + c);
    ushort4 pk; pk.x=f2b(v.x); pk.y=f2b(v.y); pk.z=f2b(v.z); pk.w=f2b(v.w);
    const int r = e>>7;
    *(ushort4*)(&At[e ^ ((r&7)<<3)]) = pk;
  }

  // W2^T fragments + bias from global (L2-hot; needed only after barrier)
  bf16x8 af[2][4];
  #pragma unroll
  for(int nt=0;nt<2;nt++){
    const int n = w*32 + nt*16 + lr;
    #pragma unroll
    for(int kk=0;kk<4;kk++)
      af[nt][kk] = *(const bf16x8*)(wt + n*128 + kk*32 + lq*8);
  }
  f32x4 bias[2];
  #pragma unroll
  for(int nt=0;nt<2;nt++){
    const float4 bv = *(const float4*)(b2 + w*32 + nt*16 + lq*4);
    bias[nt] = (f32x4){bv.x, bv.y, bv.z, bv.w};
  }
  __syncthreads();

  // g2 column sums over the 16 i's (bf16-sourced; error << tolerance)
  {
    const int dj = w, pp = lane;
    const uint* a32 = (const uint*)At;
    float s0=0.f, s1=0.f;
    #pragma unroll
    for(int di=0;di<16;di++){
      const int r = di*4+dj;
      uint u = a32[(r*64 + pp) ^ ((r&7)<<2)];
      s0 += b2f_lo(u); s1 += b2f_hi(u);
    }
    float* dst = g2acc + ((size_t)spin*NN + (j0+dj))*PAIR + pp*2;
    atomicAdd(dst, s0); atomicAdd(dst+1, s1);
  }

  // GEMM: D[n][m], A-op = W2^T frags (regs), B-op = At frags (swizzled LDS)
  f32x4 acc[4][2];
  #pragma unroll
  for(int mt=0;mt<4;mt++){
    acc[mt][0] = bias[0];
    acc[mt][1] = bias[1];
  }
  #pragma unroll
  for(int kk=0;kk<4;kk++){
    bf16x8 bfr[4];
    #pragma unroll
    for(int mt=0;mt<4;mt++){
      const int m = mt*16 + lr;                 // (m&7) == (lr&7)
      const int e = m*128 + kk*32 + lq*8;
      bfr[mt] = *(const bf16x8*)(&At[e ^ ((lr&7)<<3)]);
    }
    #pragma unroll
    for(int mt=0;mt<4;mt++){
      acc[mt][0] = __builtin_amdgcn_mfma_f32_16x16x32_bf16(af[0][kk], bfr[mt], acc[mt][0], 0,0,0);
      acc[mt][1] = __builtin_amdgcn_mfma_f32_16x16x32_bf16(af[1][kk], bfr[mt], acc[mt][1], 0,0,0);
    }
  }

  // epilogue: tanh*gain + residual (f32 re-read, L1/L2 hot), regular stores
  #pragma unroll
  for(int mt=0;mt<4;mt++){
    const int m = mt*16 + lr;
    const size_t base = ((size_t)(i0 + (m>>2))*NN + (j0 + (m&3)))*PAIR;
    #pragma unroll
    for(int nt=0;nt<2;nt++){
      const int nb = w*32 + nt*16 + lq*4;
      const float4 rr = *(const float4*)(h_two + base + nb);
      f32x4 o;
      o[0] = (rr.x + GAINv*tanh_fast(acc[mt][nt][0]))*RS2;
      o[1] = (rr.y + GAINv*tanh_fast(acc[mt][nt][1]))*RS2;
      o[2] = (rr.z + GAINv*tanh_fast(acc[mt][nt][2]))*RS2;
      o[3] = (rr.w + GAINv*tanh_fast(acc[mt][nt][3]))*RS2;
      *(f32x4*)(out_h2 + base + nb) = o;
    }
  }
}

// ---------------- k4: h_one path — 2 rows/block (256 blocks = 1/CU) ---------------
__global__ __launch_bounds__(256) void k4_hone(
    const float* __restrict__ h_one,
    const float* __restrict__ w1,
    const float* __restrict__ b1,
    const float* __restrict__ g2acc,
    const float* __restrict__ gtermpart,
    float* __restrict__ out_h1)
{
  __shared__ float onein[2][512];
  const int n  = threadIdx.x;
  const int r0 = blockIdx.x*2;
  #pragma unroll
  for(int rr=0; rr<2; rr++){
    onein[rr][n] = h_one[(size_t)(r0+rr)*SINGLE + n];
    int sp = n>>7, p = n&127;
    onein[rr][256+n] = g2acc[((size_t)sp*NN + (r0+rr))*PAIR + p] * (1.f/256.f);
  }
  float gt = 0.f;
  #pragma unroll
  for(int bb=0;bb<8;bb++) gt += gtermpart[bb*256+n];
  __syncthreads();
  float a0=0.f, a1=0.f;
  for(int f=0; f<512; f++){
    float wv = w1[(size_t)f*SINGLE + n];
    a0 += onein[0][f]*wv;
    a1 += onein[1][f]*wv;
  }
  const float bn = b1[n];
  float x0 = (a0 + bn + gt)*RS2;
  float x1 = (a1 + bn + gt)*RS2;
  out_h1[(size_t)r0*SINGLE + n]     = (onein[0][n] + GAINv*tanh_fast(x0))*RS2;
  out_h1[(size_t)(r0+1)*SINGLE + n] = (onein[1][n] + GAINv*tanh_fast(x1))*RS2;
}

extern "C" void kernel_launch(void* const* d_in, const int* in_sizes, int n_in,
                              void* d_out, int out_size, void* d_ws, size_t ws_size,
                              hipStream_t stream)
{
  const float* h_one = (const float*)d_in[0];
  const float* h_two = (const float*)d_in[1];
  const float* W1    = (const float*)d_in[2];
  const float* b1    = (const float*)d_in[3];
  const float* Wg    = (const float*)d_in[4];
  const float* W2    = (const float*)d_in[5];
  const float* b2    = (const float*)d_in[6];

  float* wsf       = (float*)d_ws;
  float* g2acc     = wsf;                        // [2][512][128] f32 sums (atomic)
  ushort* wt       = (ushort*)(wsf + 131072);    // W2^T bf16 [n][k], linear
  float* g1part    = wsf + 139264;               // [8][256] spin partial sums
  float* gtermpart = wsf + 141312;               // [8][256] gterm partials

  float* out_h1 = (float*)d_out;
  float* out_h2 = out_h1 + 131072;

  k1_prep <<<24,   256, 0, stream>>>(h_one, W2, g1part, wt, g2acc);
  k2_gterm<<<8,    256, 0, stream>>>(g1part, Wg, gtermpart);
  k3_htwo <<<4096, 256, 0, stream>>>(h_two, b2, wt, g2acc, out_h2);
  k4_hone <<<256,  256, 0, stream>>>(h_one, W1, b1, g2acc, gtermpart, out_h1);
}